// Round 16
// baseline (385.797 us; speedup 1.0000x reference)
//
#include <hip/hip_runtime.h>
#include <hip/hip_bf16.h>
#include <math.h>

// Problem constants (LightGFormer): B=16, N=512, D=256, L=4, H=8, dk=32, Dff=1024
#define BDIM 16
#define NSEQ 512
#define DMODEL 256
#define NLAYER 4
#define NHEAD 8
#define DK 32
#define DFF 1024
#define BN (BDIM * NSEQ)          // 8192 tokens
#define ND (NSEQ * DMODEL)        // 131072

typedef __bf16 bf16x8 __attribute__((ext_vector_type(8)));
typedef float floatx4 __attribute__((ext_vector_type(4)));
typedef unsigned uint32x2 __attribute__((ext_vector_type(2)));

// RNE float->bf16 bits
static __device__ __forceinline__ unsigned short f2bf(float f) {
    unsigned u = __float_as_uint(f);
    unsigned r = (u + 0x7FFFu + ((u >> 16) & 1u)) >> 16;
    return (unsigned short)r;
}
static __device__ __forceinline__ float bf2f(unsigned short u) {
    return __uint_as_float(((unsigned)u) << 16);
}

// async 16-byte global->LDS copy (wave-uniform LDS base + lane*16 required)
static __device__ __forceinline__ void async_ld16(const unsigned short* g,
                                                  unsigned short* l) {
    __builtin_amdgcn_global_load_lds(
        (const __attribute__((address_space(1))) unsigned int*)g,
        (__attribute__((address_space(3))) unsigned int*)l, 16, 0, 0);
}

// sigmoid-form tanh-approx GELU, |err| < 1e-3 vs exact
static __device__ __forceinline__ float gelu_f(float c) {
    float u = 0.7978845608028654f * (c + 0.044715f * c * c * c);
    return c * (1.f / (1.f + __expf(-2.f * u)));
}

static __device__ __forceinline__ unsigned cvtpk(float lo, float hi) {
    unsigned r;
    asm("v_cvt_pk_bf16_f32 %0, %1, %2" : "=v"(r) : "v"(lo), "v"(hi));
    return r;
}

// ---------------------------------------------------------------------------
// Weight conversions + mask pack in ONE dispatch (R12-proven).
// blocks [0,3072)    : Wq/Wk/Wv [L,K,N]->[L,N,K] bf16 (qkv LDS kernel layout)
// blocks [3072,4096) : Wo  -> frag-direct wo_s
// blocks [4096,8192) : W1  -> frag-direct w1_s
// blocks [8192,9216) : W2  -> frag-direct w2_s
// blocks [9216,9248) : mask -> bitmask
// ---------------------------------------------------------------------------
__global__ void conv_all_kernel(const float* __restrict__ Wq, const float* __restrict__ Wk,
                                const float* __restrict__ Wv, const float* __restrict__ Wo,
                                const float* __restrict__ W1, const float* __restrict__ W2,
                                const int* __restrict__ mask,
                                unsigned short* __restrict__ wqT, unsigned short* __restrict__ wkT,
                                unsigned short* __restrict__ wvT,
                                unsigned short* __restrict__ wo_s,
                                unsigned short* __restrict__ w1_s, unsigned short* __restrict__ w2_s,
                                unsigned* __restrict__ bits) {
    int blk = blockIdx.x, tid = threadIdx.x;
    if (blk < 3072) {
        int i = blk * 256 + tid;
        int sel = i >> 18;
        int j = i & 262143;
        int l = j >> 16, rem = j & 65535, kk = rem >> 8, n = rem & 255;
        const float* src = sel == 0 ? Wq : sel == 1 ? Wk : Wv;
        unsigned short* dst = sel == 0 ? wqT : sel == 1 ? wkT : wvT;
        dst[(size_t)l * 65536 + n * 256 + kk] = f2bf(src[j]);
    } else if (blk < 4096) {
        int i = (blk - 3072) * 256 + tid;
        int l = i >> 16, o = i & 65535;
        int j = o & 7, quad = (o >> 3) & 3, l16 = (o >> 5) & 15;
        int kt = (o >> 9) & 7, cg = (o >> 12) & 15;
        int k = kt * 32 + (j >> 2) * 16 + quad * 4 + (j & 3);
        int dout = cg * 16 + l16;
        wo_s[(size_t)l * 65536 + o] = f2bf(Wo[(size_t)l * 65536 + k * 256 + dout]);
    } else if (blk < 8192) {
        int i = (blk - 4096) * 256 + tid;
        int l = i >> 18, o = i & 262143;
        int j = o & 7, quad = (o >> 3) & 3, l16 = (o >> 5) & 15;
        int kt = (o >> 9) & 7, cg = (o >> 12) & 63;
        int k = kt * 32 + (j >> 2) * 16 + quad * 4 + (j & 3);
        int dout = cg * 16 + l16;
        w1_s[(size_t)l * 262144 + o] = f2bf(W1[(size_t)l * 262144 + k * 1024 + dout]);
    } else if (blk < 9216) {
        int i = (blk - 8192) * 256 + tid;
        int l = i >> 16, o = i & 65535;
        int j = o & 7, quad = (o >> 3) & 3, l16 = (o >> 5) & 15;
        int kt = (o >> 9) & 15, cg = (o >> 13) & 7;
        int k = kt * 32 + (j >> 2) * 16 + quad * 4 + (j & 3);
        int dout = cg * 16 + l16;
        w2_s[(size_t)l * 65536 + o] = f2bf(W2[(size_t)l * 65536 + k * 128 + dout]);
    } else {
        int w = (blk - 9216) * 256 + tid;   // 0..8191
        int r = w >> 4, wi = w & 15;
        const int* src = mask + r * NSEQ + wi * 32;
        unsigned acc = 0;
#pragma unroll
        for (int j = 0; j < 32; j++) acc |= (src[j] != 0 ? 1u : 0u) << j;
        bits[w] = acc;
    }
}

// ---------------------------------------------------------------------------
// x = input + pos (fp32 + bf16 row-major) ; xv = input_v + pos (bf16 only)
// ---------------------------------------------------------------------------
__global__ void add_pos_kernel(const float* __restrict__ in,
                               const float* __restrict__ inv,
                               const float* __restrict__ pos,
                               float* __restrict__ x,
                               unsigned short* __restrict__ xb,
                               unsigned short* __restrict__ xvb,
                               int total) {
    int i = blockIdx.x * blockDim.x + threadIdx.x;
    if (i < total) {
        float pe = pos[i % ND];
        float a = in[i] + pe;
        float b = inv[i] + pe;
        x[i] = a;
        xb[i] = f2bf(a);
        xvb[i] = f2bf(b);
    }
}

// ---------------------------------------------------------------------------
// Fused QKV GEMM (proven R3/R4 structure). grid (6,64).
// ---------------------------------------------------------------------------
__global__ __launch_bounds__(256) void qkv_mfma_kernel(
        const unsigned short* __restrict__ xb,
        const unsigned short* __restrict__ xvb,
        const unsigned short* __restrict__ WqT, const unsigned short* __restrict__ WkT,
        const unsigned short* __restrict__ WvT,
        const float* __restrict__ bq, const float* __restrict__ bk,
        const float* __restrict__ bv,
        unsigned short* __restrict__ qo, unsigned short* __restrict__ ko,
        unsigned short* __restrict__ vo) {
    int proj = blockIdx.x >> 1;
    const unsigned short* A  = (proj == 2) ? xvb : xb;
    const unsigned short* Bt = (proj == 0) ? WqT : (proj == 1) ? WkT : WvT;
    const float* bias        = (proj == 0) ? bq  : (proj == 1) ? bk  : bv;
    unsigned short* Cb       = (proj == 0) ? qo  : (proj == 1) ? ko  : vo;
    float qscale = (proj == 0) ? 0.17677669529663687f : 1.f;

    __shared__ unsigned short As[128 * 32];
    __shared__ unsigned short Bs[128 * 32];
    int tid = threadIdx.x;
    int wave = tid >> 6, lane = tid & 63;
    int rowBase = blockIdx.y * 128, colBase = (blockIdx.x & 1) * 128;
    int m0w = (wave & 1) * 64, n0w = (wave >> 1) * 64;
    int lr = lane & 15, quad = lane >> 4;
    int qx = quad ^ (lr & 3);

    floatx4 acc[4][4];
#pragma unroll
    for (int mi = 0; mi < 4; mi++)
#pragma unroll
        for (int nj = 0; nj < 4; nj++) acc[mi][nj] = (floatx4)0.0f;

    for (int kt = 0; kt < DMODEL; kt += 32) {
#pragma unroll
        for (int t = 0; t < 2; t++) {
            int idx = t * 256 + tid;
            int row = idx >> 2, kv8 = ((idx ^ row) & 3) * 8;
            async_ld16(A + (size_t)(rowBase + row) * DMODEL + kt + kv8, &As[idx * 8]);
            async_ld16(Bt + (size_t)(colBase + row) * DMODEL + kt + kv8, &Bs[idx * 8]);
        }
        __syncthreads();
        bf16x8 af[4], bfr[4];
#pragma unroll
        for (int mi = 0; mi < 4; mi++)
            af[mi] = *(const bf16x8*)&As[(m0w + mi * 16 + lr) * 32 + qx * 8];
#pragma unroll
        for (int nj = 0; nj < 4; nj++)
            bfr[nj] = *(const bf16x8*)&Bs[(n0w + nj * 16 + lr) * 32 + qx * 8];
#pragma unroll
        for (int mi = 0; mi < 4; mi++)
#pragma unroll
            for (int nj = 0; nj < 4; nj++)
                acc[mi][nj] = __builtin_amdgcn_mfma_f32_16x16x32_bf16(
                    af[mi], bfr[nj], acc[mi][nj], 0, 0, 0);
        __syncthreads();
    }

#pragma unroll
    for (int mi = 0; mi < 4; mi++) {
#pragma unroll
        for (int r = 0; r < 4; r++) {
            int grow = rowBase + m0w + mi * 16 + quad * 4 + r;
#pragma unroll
            for (int nj = 0; nj < 4; nj++) {
                int gcol = colBase + n0w + nj * 16 + lr;
                float c = (acc[mi][nj][r] + bias[gcol]) * qscale;
                size_t off = ((size_t)((grow >> 9) * 8 + (gcol >> 5)) << 14)
                           + (size_t)(grow & 511) * 32 + (gcol & 31);
                Cb[off] = f2bf(c);
            }
        }
    }
}

// ---------------------------------------------------------------------------
// FUSED per-layer tail v5 (R12-proven): 512 threads / 8 waves per panel.
// ---------------------------------------------------------------------------
__global__ __launch_bounds__(512, 4) void ffn_fused_kernel(
        const unsigned short* __restrict__ ab_f,  // frag-direct attn out
        const unsigned short* __restrict__ wo_s,
        const unsigned short* __restrict__ w1_s,
        const unsigned short* __restrict__ w2_s,
        const float* __restrict__ bo,
        const float* __restrict__ g1, const float* __restrict__ be1,
        const float* __restrict__ b1,             // [1024]
        const float* __restrict__ b2,             // [128]
        const float* __restrict__ g2, const float* __restrict__ be2,
        const float* __restrict__ gf, const float* __restrict__ bf_,
        float* __restrict__ xf, unsigned short* __restrict__ xb,
        float* __restrict__ outF, int finalize) {
    __shared__ unsigned short X1s[8 * 512];    // 8KB  x1 tr-tiles [ct][colL*16+tok]
    __shared__ unsigned short Hs[16 * 512];    // 16KB h tr-tiles (per group)
    __shared__ float redA[16][8], redB[16][8];
    __shared__ float redC[16][8], redD[16][8];
    __shared__ float redE[16][8], redF[16][8];

    int tid = threadIdx.x;
    int w = tid >> 6, lane = tid & 63, l16 = lane & 15, quad = lane >> 4;
    int bid = blockIdx.x;                      // token panel (16 tokens)
    int rowBase = bid * 16;
    int fo = (l16 * 4 + quad) * 8;             // frag-direct lane offset (elems)

#define TR2(d0, d1, addr)                                                  \
    asm volatile("ds_read_b64_tr_b16 %0, %2\n\t"                           \
                 "ds_read_b64_tr_b16 %1, %2 offset:512"                    \
                 : "=&v"(d0), "=&v"(d1) : "v"(addr))

    // preload ALL scalar params + residual x0 now (latency hides under Phase A)
    float bo_r[2], g1_r[2], be1_r[2], g2_r[2], be2_r[2], gf_r[2], bfr_[2];
#pragma unroll
    for (int cg = 0; cg < 2; cg++) {
        int colA = w * 32 + cg * 16 + l16;
        bo_r[cg] = bo[colA]; g1_r[cg] = g1[colA]; be1_r[cg] = be1[colA];
        int colC = cg * 128 + w * 16 + l16;
        g2_r[cg] = g2[colC]; be2_r[cg] = be2[colC];
        gf_r[cg] = gf[colC]; bfr_[cg] = bf_[colC];
    }
    float b1_r[2][4];
#pragma unroll
    for (int g = 0; g < 2; g++)
#pragma unroll
        for (int c = 0; c < 4; c++)
            b1_r[g][c] = b1[g * 512 + w * 64 + c * 16 + l16];
    float b2_r = b2[w * 16 + l16];
    float x0r[4][2];
#pragma unroll
    for (int r = 0; r < 4; r++)
#pragma unroll
        for (int cg = 0; cg < 2; cg++)
            x0r[r][cg] = xf[(size_t)(rowBase + quad * 4 + r) * 256 + w * 32 + cg * 16 + l16];

    // ---- Phase A: x1 = LN1(x0 + ab@Wo + bo); wave owns 32 dout cols ----
    floatx4 accA[2];
    accA[0] = (floatx4)0.0f; accA[1] = (floatx4)0.0f;

    bf16x8 afQ[4], bwQ[4][2];
#pragma unroll
    for (int p = 0; p < 4; p++) {
        afQ[p] = *(const bf16x8*)(ab_f + ((size_t)bid * 8 + p) * 512 + fo);
#pragma unroll
        for (int cg = 0; cg < 2; cg++)
            bwQ[p][cg] = *(const bf16x8*)(wo_s + ((size_t)((w * 2 + cg) * 8 + p)) * 512 + fo);
    }

#pragma unroll
    for (int kt = 0; kt < 8; kt++) {
        int sl = kt & 3;
#pragma unroll
        for (int cg = 0; cg < 2; cg++)
            accA[cg] = __builtin_amdgcn_mfma_f32_16x16x32_bf16(afQ[sl], bwQ[sl][cg], accA[cg], 0, 0, 0);
        if (kt < 4) {
            afQ[sl] = *(const bf16x8*)(ab_f + ((size_t)bid * 8 + kt + 4) * 512 + fo);
#pragma unroll
            for (int cg = 0; cg < 2; cg++)
                bwQ[sl][cg] = *(const bf16x8*)(wo_s + ((size_t)((w * 2 + cg) * 8 + kt + 4)) * 512 + fo);
        }
    }

    // LN1 partials
#pragma unroll
    for (int r = 0; r < 4; r++) {
        int tok = quad * 4 + r;
        float s = 0.f, s2 = 0.f;
#pragma unroll
        for (int cg = 0; cg < 2; cg++) {
            float v = accA[cg][r] + bo_r[cg] + x0r[r][cg];
            accA[cg][r] = v; s += v; s2 += v * v;
        }
#pragma unroll
        for (int off = 1; off <= 8; off <<= 1) {
            s += __shfl_xor(s, off);
            s2 += __shfl_xor(s2, off);
        }
        if (l16 == 0) { redA[tok][w] = s; redB[tok][w] = s2; }
    }
    __syncthreads();
#pragma unroll
    for (int r = 0; r < 4; r++) {
        int tok = quad * 4 + r;
        float ts = 0.f, tq = 0.f;
#pragma unroll
        for (int ww = 0; ww < 8; ww++) { ts += redA[tok][ww]; tq += redB[tok][ww]; }
        float mean = ts * (1.f / 256.f);
        float var = tq * (1.f / 256.f) - mean * mean;
        float rstd = rsqrtf(var + 1e-5f);
#pragma unroll
        for (int cg = 0; cg < 2; cg++)
            accA[cg][r] = (accA[cg][r] - mean) * rstd * g1_r[cg] + be1_r[cg];
    }
    // write X1s tr-tile ct=w: value(tok,col) at [col>>5][(col&31)*16+tok]
#pragma unroll
    for (int cg = 0; cg < 2; cg++) {
        uint32x2 pk;
        pk[0] = cvtpk(accA[cg][0], accA[cg][1]);
        pk[1] = cvtpk(accA[cg][2], accA[cg][3]);
        *(uint32x2*)&X1s[w * 512 + (cg * 16 + l16) * 16 + quad * 4] = pk;
    }
    __syncthreads();

    unsigned x1addr = (unsigned)(size_t)&X1s[0] + (unsigned)(lane * 8);
    unsigned haddr  = (unsigned)(size_t)&Hs[0]  + (unsigned)(lane * 8);

    floatx4 y[2];
    y[0] = (floatx4)0.0f; y[1] = (floatx4)0.0f;

#pragma unroll
    for (int g = 0; g < 2; g++) {
        // ---- Phase B: h = gelu(x1 @ W1 + b1); wave owns 64 dff cols ----
        floatx4 accB[4];
#pragma unroll
        for (int c = 0; c < 4; c++) accB[c] = (floatx4)0.0f;

        uint32x2 tA0, tA1, tB0, tB1;
        TR2(tA0, tA1, x1addr);
        TR2(tB0, tB1, x1addr + 1024u);
        bf16x8 bwB[2][4];
#pragma unroll
        for (int p = 0; p < 2; p++)
#pragma unroll
            for (int c = 0; c < 4; c++)
                bwB[p][c] = *(const bf16x8*)(w1_s +
                    ((size_t)((g * 32 + w * 4 + c) * 8 + p)) * 512 + fo);

#pragma unroll
        for (int kt = 0; kt < 8; kt++) {
            if (kt < 7) asm volatile("s_waitcnt lgkmcnt(2)");
            else        asm volatile("s_waitcnt lgkmcnt(0)");
            __builtin_amdgcn_sched_barrier(0);
            union { bf16x8 v8; uint32x2 u[2]; } afu;
            if ((kt & 1) == 0) { afu.u[0] = tA0; afu.u[1] = tA1; }
            else               { afu.u[0] = tB0; afu.u[1] = tB1; }
            if (kt < 6) {
                if ((kt & 1) == 0) TR2(tA0, tA1, x1addr + (unsigned)((kt + 2) * 1024));
                else               TR2(tB0, tB1, x1addr + (unsigned)((kt + 2) * 1024));
            }
            int sl = kt & 1;
#pragma unroll
            for (int c = 0; c < 4; c++)
                accB[c] = __builtin_amdgcn_mfma_f32_16x16x32_bf16(afu.v8, bwB[sl][c], accB[c], 0, 0, 0);
            if (kt < 6) {
#pragma unroll
                for (int c = 0; c < 4; c++)
                    bwB[sl][c] = *(const bf16x8*)(w1_s +
                        ((size_t)((g * 32 + w * 4 + c) * 8 + kt + 2)) * 512 + fo);
            }
        }
        // epilogue B: bias+gelu, write Hs tr-tiles (wave-disjoint: ct = w*2+(c>>1))
#pragma unroll
        for (int c = 0; c < 4; c++) {
            float bb = b1_r[g][c];
            float o0 = gelu_f(accB[c][0] + bb);
            float o1 = gelu_f(accB[c][1] + bb);
            float o2 = gelu_f(accB[c][2] + bb);
            float o3 = gelu_f(accB[c][3] + bb);
            int ct = w * 2 + (c >> 1), colL = (c & 1) * 16 + l16;
            uint32x2 pk;
            pk[0] = cvtpk(o0, o1);
            pk[1] = cvtpk(o2, o3);
            *(uint32x2*)&Hs[ct * 512 + colL * 16 + quad * 4] = pk;
        }
        __syncthreads();

        // ---- Phase C: y[g] += h @ W2; wave owns 16 dout cols ----
        TR2(tA0, tA1, haddr);
        TR2(tB0, tB1, haddr + 1024u);
        bf16x8 bwC[4];
#pragma unroll
        for (int p = 0; p < 4; p++)
            bwC[p] = *(const bf16x8*)(w2_s + ((size_t)(w * 16 + p)) * 512 + fo);

#pragma unroll
        for (int kt = 0; kt < 16; kt++) {
            if (kt < 15) asm volatile("s_waitcnt lgkmcnt(2)");
            else         asm volatile("s_waitcnt lgkmcnt(0)");
            __builtin_amdgcn_sched_barrier(0);
            union { bf16x8 v8; uint32x2 u[2]; } afu;
            if ((kt & 1) == 0) { afu.u[0] = tA0; afu.u[1] = tA1; }
            else               { afu.u[0] = tB0; afu.u[1] = tB1; }
            if (kt < 14) {
                if ((kt & 1) == 0) TR2(tA0, tA1, haddr + (unsigned)((kt + 2) * 1024));
                else               TR2(tB0, tB1, haddr + (unsigned)((kt + 2) * 1024));
            }
            y[g] = __builtin_amdgcn_mfma_f32_16x16x32_bf16(afu.v8, bwC[kt & 3], y[g], 0, 0, 0);
            if (kt < 12)
                bwC[kt & 3] = *(const bf16x8*)(w2_s + ((size_t)(w * 16 + kt + 4)) * 512 + fo);
        }
        if (g == 0) __syncthreads();   // protect Hs before group 1 rewrites
    }
#undef TR2

    // ---- LN2 (+ optional final LN); lane holds cols g*128 + w*16 + l16 ----
#pragma unroll
    for (int r = 0; r < 4; r++) {
        int tok = quad * 4 + r;
        float s = 0.f, s2 = 0.f;
#pragma unroll
        for (int g = 0; g < 2; g++) {
            int col = g * 128 + w * 16 + l16;
            float x1v = bf2f(X1s[(col >> 5) * 512 + (col & 31) * 16 + tok]);
            float v = y[g][r] + b2_r + x1v;
            y[g][r] = v; s += v; s2 += v * v;
        }
#pragma unroll
        for (int off = 1; off <= 8; off <<= 1) {
            s += __shfl_xor(s, off);
            s2 += __shfl_xor(s2, off);
        }
        if (l16 == 0) { redC[tok][w] = s; redD[tok][w] = s2; }
    }
    __syncthreads();

    if (!finalize) {
#pragma unroll
        for (int r = 0; r < 4; r++) {
            int tok = quad * 4 + r;
            float ts = 0.f, tq = 0.f;
#pragma unroll
            for (int ww = 0; ww < 8; ww++) { ts += redC[tok][ww]; tq += redD[tok][ww]; }
            float mean = ts * (1.f / 256.f);
            float var = tq * (1.f / 256.f) - mean * mean;
            float rstd = rsqrtf(var + 1e-5f);
#pragma unroll
            for (int g = 0; g < 2; g++) {
                int col = g * 128 + w * 16 + l16;
                float o = (y[g][r] - mean) * rstd * g2_r[g] + be2_r[g];
                xf[(size_t)(rowBase + tok) * 256 + col] = o;
                xb[(size_t)(rowBase + tok) * 256 + col] = f2bf(o);
            }
        }
    } else {
#pragma unroll
        for (int r = 0; r < 4; r++) {
            int tok = quad * 4 + r;
            float ts = 0.f, tq = 0.f;
#pragma unroll
            for (int ww = 0; ww < 8; ww++) { ts += redC[tok][ww]; tq += redD[tok][ww]; }
            float mean = ts * (1.f / 256.f);
            float var = tq * (1.f / 256.f) - mean * mean;
            float rstd = rsqrtf(var + 1e-5f);
            float s3 = 0.f, q3 = 0.f;
#pragma unroll
            for (int g = 0; g < 2; g++) {
                float o = (y[g][r] - mean) * rstd * g2_r[g] + be2_r[g];
                y[g][r] = o; s3 += o; q3 += o * o;
            }
#pragma unroll
            for (int off = 1; off <= 8; off <<= 1) {
                s3 += __shfl_xor(s3, off);
                q3 += __shfl_xor(q3, off);
            }
            if (l16 == 0) { redE[tok][w] = s3; redF[tok][w] = q3; }
        }
        __syncthreads();
#pragma unroll
        for (int r = 0; r < 4; r++) {
            int tok = quad * 4 + r;
            float ts = 0.f, tq = 0.f;
#pragma unroll
            for (int ww = 0; ww < 8; ww++) { ts += redE[tok][ww]; tq += redF[tok][ww]; }
            float mean = ts * (1.f / 256.f);
            float var = tq * (1.f / 256.f) - mean * mean;
            float rstd = rsqrtf(var + 1e-5f);
#pragma unroll
            for (int g = 0; g < 2; g++) {
                int col = g * 128 + w * 16 + l16;
                outF[(size_t)(rowBase + tok) * 256 + col]
                    = (y[g][r] - mean) * rstd * gf_r[g] + bfr_[g];
            }
        }
    }
}

// ---------------------------------------------------------------------------
// MFMA attention v2 (pair-batched, R12-proven) — SINGLE CHANGE this round:
// __launch_bounds__(256) without the min-waves clause. The (256,4) form
// capped VGPR at 128, right at this kernel's ~120-135 peak -> likely spill /
// over-constrained regalloc. Letting the allocator take ~140-160 VGPRs
// (3 blocks/CU natural) removes that pressure.
// ---------------------------------------------------------------------------
__global__ __launch_bounds__(256) void attn_mfma_kernel(
        const unsigned short* __restrict__ q, const unsigned short* __restrict__ k,
        const unsigned short* __restrict__ v, unsigned short* __restrict__ ab_f,
        const unsigned* __restrict__ mbits_g, int use_mask) {
    int bid = blockIdx.x;
    int qg = bid >> 7;          // 0..7
    int bh = bid & 127;         // XCD = bh & 7 = h
    int h = bh & 7, b = bh >> 3;
    int tid = threadIdx.x;

    __shared__ unsigned short Vs[2][NSEQ * 16];     // 32KB  [db][k*16+d]

    const unsigned short* kbase = k + (size_t)(b * 8 + h) * (NSEQ * DK);
    const unsigned short* vbase = v + (size_t)(b * 8 + h) * (NSEQ * DK);

#pragma unroll
    for (int db = 0; db < 2; db++) {
#pragma unroll
        for (int t = 0; t < 4; t++) {
            int c = t * 256 + tid;                  // 0..1023
            int kk = c >> 1, half = c & 1;
            async_ld16(vbase + (size_t)kk * 32 + db * 16 + half * 8,
                       &Vs[db][c * 8]);
        }
    }

    int wave = tid >> 6, lane = tid & 63, l16 = lane & 15, quad = lane >> 4;
    int qbase = qg * 64 + wave * 16;

    bf16x8 qf = *(const bf16x8*)(q + ((size_t)(b * 8 + h) * NSEQ + qbase + l16) * 32 + quad * 8);

    unsigned mw[16];
    if (use_mask) {
        const uint4* mr = (const uint4*)(mbits_g + (size_t)(qbase + l16) * 16);
#pragma unroll
        for (int w = 0; w < 4; w++) *(uint4*)&mw[w * 4] = mr[w];
    } else {
#pragma unroll
        for (int w = 0; w < 16; w++) mw[w] = 0;
    }
    __syncthreads();

    unsigned va0 = (unsigned)(size_t)&Vs[0][0] + (unsigned)(lane * 8);
    unsigned va1 = (unsigned)(size_t)&Vs[1][0] + (unsigned)(lane * 8);

    const unsigned short* kfrag = kbase + (size_t)l16 * DK + quad * 8;

    floatx4 oT0 = (floatx4)0.f, oT1 = (floatx4)0.f;
    float m_run = -INFINITY, l_part = 0.f;

    uint32x2 t00, t01, t02, t03, t10, t11, t12, t13;
    // 8 tr-reads for pair cp: tiles 2cp (offsets 0,512) and 2cp+1 (1024,1536)
#define TR_ISSUE8(cp)                                                      \
    asm volatile("ds_read_b64_tr_b16 %0, %8\n\t"                           \
                 "ds_read_b64_tr_b16 %1, %8 offset:512\n\t"                \
                 "ds_read_b64_tr_b16 %2, %8 offset:1024\n\t"               \
                 "ds_read_b64_tr_b16 %3, %8 offset:1536\n\t"               \
                 "ds_read_b64_tr_b16 %4, %9\n\t"                           \
                 "ds_read_b64_tr_b16 %5, %9 offset:512\n\t"                \
                 "ds_read_b64_tr_b16 %6, %9 offset:1024\n\t"               \
                 "ds_read_b64_tr_b16 %7, %9 offset:1536"                   \
                 : "=&v"(t00), "=&v"(t01), "=&v"(t02), "=&v"(t03),         \
                   "=&v"(t10), "=&v"(t11), "=&v"(t12), "=&v"(t13)          \
                 : "v"(va0 + (unsigned)((cp) * 2048)),                     \
                   "v"(va1 + (unsigned)((cp) * 2048)))
    TR_ISSUE8(0);

    bf16x8 k0 = *(const bf16x8*)(kfrag);
    bf16x8 k1 = *(const bf16x8*)(kfrag + 16 * DK);
    bf16x8 k2 = *(const bf16x8*)(kfrag + 32 * DK);
    bf16x8 k3 = *(const bf16x8*)(kfrag + 48 * DK);

#pragma unroll
    for (int cp = 0; cp < 8; cp++) {
        floatx4 s0 = __builtin_amdgcn_mfma_f32_16x16x32_bf16(k0, qf, (floatx4)0.f, 0, 0, 0);
        floatx4 s1 = __builtin_amdgcn_mfma_f32_16x16x32_bf16(k1, qf, (floatx4)0.f, 0, 0, 0);
        floatx4 s2 = __builtin_amdgcn_mfma_f32_16x16x32_bf16(k2, qf, (floatx4)0.f, 0, 0, 0);
        floatx4 s3 = __builtin_amdgcn_mfma_f32_16x16x32_bf16(k3, qf, (floatx4)0.f, 0, 0, 0);

        bf16x8 k0n, k1n, k2n, k3n;
        if (cp < 7) {
            const unsigned short* kn = kfrag + (size_t)((cp + 1) * 64) * DK;
            k0n = *(const bf16x8*)(kn);
            k1n = *(const bf16x8*)(kn + 16 * DK);
            k2n = *(const bf16x8*)(kn + 32 * DK);
            k3n = *(const bf16x8*)(kn + 48 * DK);
        }

        float sv[16];
#pragma unroll
        for (int r = 0; r < 4; r++) {
            sv[r] = s0[r]; sv[4 + r] = s1[r];
            sv[8 + r] = s2[r]; sv[12 + r] = s3[r];
        }
        if (use_mask) {
            unsigned wb0 = mw[2 * cp], wb1 = mw[2 * cp + 1];
#pragma unroll
            for (int r = 0; r < 4; r++) {
                if ((wb0 >> (quad * 4 + r)) & 1)        sv[r]      = -INFINITY;
                if ((wb0 >> (16 + quad * 4 + r)) & 1)   sv[4 + r]  = -INFINITY;
                if ((wb1 >> (quad * 4 + r)) & 1)        sv[8 + r]  = -INFINITY;
                if ((wb1 >> (16 + quad * 4 + r)) & 1)   sv[12 + r] = -INFINITY;
            }
        }
        float mx = sv[0];
#pragma unroll
        for (int j = 1; j < 16; j++) mx = fmaxf(mx, sv[j]);
        mx = fmaxf(mx, __shfl_xor(mx, 16));
        mx = fmaxf(mx, __shfl_xor(mx, 32));
        if (!__all(mx <= m_run)) {
            float mnew = fmaxf(m_run, mx);
            float corr = (m_run == mnew) ? 1.f : __expf(m_run - mnew);
            l_part *= corr;
            oT0 *= corr; oT1 *= corr;
            m_run = mnew;
        }
        float p[16];
#pragma unroll
        for (int j = 0; j < 16; j++) {
            float e = __expf(sv[j] - m_run);
            p[j] = (sv[j] > -INFINITY) ? e : 0.f;
            l_part += p[j];
        }
        union { bf16x8 v8; unsigned u[4]; } pf0, pf1;
#pragma unroll
        for (int j = 0; j < 4; j++) {
            pf0.u[j] = cvtpk(p[2 * j], p[2 * j + 1]);
            pf1.u[j] = cvtpk(p[8 + 2 * j], p[8 + 2 * j + 1]);
        }

        asm volatile("s_waitcnt lgkmcnt(0)");
        __builtin_amdgcn_sched_barrier(0);
        union { bf16x8 v8; uint32x2 u[2]; } av0, av1, av2, av3;
        av0.u[0] = t00; av0.u[1] = t01;   // tile 2cp,   d block 0
        av2.u[0] = t02; av2.u[1] = t03;   // tile 2cp+1, d block 0
        av1.u[0] = t10; av1.u[1] = t11;   // tile 2cp,   d block 1
        av3.u[0] = t12; av3.u[1] = t13;   // tile 2cp+1, d block 1

        oT0 = __builtin_amdgcn_mfma_f32_16x16x32_bf16(av0.v8, pf0.v8, oT0, 0, 0, 0);
        oT1 = __builtin_amdgcn_mfma_f32_16x16x32_bf16(av1.v8, pf0.v8, oT1, 0, 0, 0);
        oT0 = __builtin_amdgcn_mfma_f32_16x16x32_bf16(av2.v8, pf1.v8, oT0, 0, 0, 0);
        oT1 = __builtin_amdgcn_mfma_f32_16x16x32_bf16(av3.v8, pf1.v8, oT1, 0, 0, 0);
        if (cp < 7) TR_ISSUE8(cp + 1);
        k0 = k0n; k1 = k1n; k2 = k2n; k3 = k3n;
    }
#undef TR_ISSUE8

    float l = l_part;
    l += __shfl_xor(l, 16);
    l += __shfl_xor(l, 32);
    float invl = (l > 0.f) ? 1.f / l : 0.f;

    // frag-direct store: panel = global_token>>4, tile kt = h
    uint4 val;
    val.x = cvtpk(oT0[0] * invl, oT0[1] * invl);
    val.y = cvtpk(oT0[2] * invl, oT0[3] * invl);
    val.z = cvtpk(oT1[0] * invl, oT1[1] * invl);
    val.w = cvtpk(oT1[2] * invl, oT1[3] * invl);
    size_t panel = (size_t)b * 32 + qg * 4 + wave;
    *(uint4*)(ab_f + (panel * 8 + h) * 512 + (l16 * 4 + quad) * 8) = val;
}

// ---------------------------------------------------------------------------
extern "C" void kernel_launch(void* const* d_in, const int* in_sizes, int n_in,
                              void* d_out, int out_size, void* d_ws, size_t ws_size,
                              hipStream_t stream) {
    const float* input  = (const float*)d_in[0];
    const float* inputv = (const float*)d_in[1];
    const float* pos    = (const float*)d_in[2];
    const float* Wq = (const float*)d_in[3];
    const float* bq = (const float*)d_in[4];
    const float* Wk = (const float*)d_in[5];
    const float* bk = (const float*)d_in[6];
    const float* Wv = (const float*)d_in[7];
    const float* bv = (const float*)d_in[8];
    const float* Wo = (const float*)d_in[9];
    const float* bo = (const float*)d_in[10];
    const float* W1 = (const float*)d_in[11];
    const float* b1 = (const float*)d_in[12];
    const float* W2 = (const float*)d_in[13];
    const float* b2 = (const float*)d_in[14];
    const float* g1 = (const float*)d_in[15];
    const float* be1 = (const float*)d_in[16];
    const float* g2 = (const float*)d_in[17];
    const float* be2 = (const float*)d_in[18];
    const float* gf = (const float*)d_in[19];
    const float* bff = (const float*)d_in[20];
    const int* mask = (const int*)d_in[21];

    float* out = (float*)d_out;

    // Workspace layout (bytes), ~37 MB
    char* wsb = (char*)d_ws;
    float* x_f  = (float*)(wsb + ((size_t)0 << 20));                    // 8 MB
    unsigned short* x_b  = (unsigned short*)(wsb + ((size_t)8 << 20));  // 4 MB
    unsigned short* xv_b = (unsigned short*)(wsb + ((size_t)12 << 20)); // 4 MB
    unsigned short* qb_b = (unsigned short*)(wsb + ((size_t)16 << 20)); // 4 MB
    unsigned short* kb_b = (unsigned short*)(wsb + ((size_t)20 << 20)); // 4 MB
    unsigned short* vb_b = (unsigned short*)(wsb + ((size_t)24 << 20)); // 4 MB
    unsigned short* ab_f = (unsigned short*)(wsb + ((size_t)28 << 20)); // 4 MB
    unsigned short* wqT = (unsigned short*)(wsb + ((size_t)32 << 20));
    unsigned short* wkT = wqT + (size_t)4 * 65536;
    unsigned short* wvT = wkT + (size_t)4 * 65536;
    unsigned short* wo_s = wvT + (size_t)4 * 65536;
    unsigned short* w1_s = wo_s + (size_t)4 * 65536;   // 4 x 262144
    unsigned short* w2_s = w1_s + (size_t)4 * 262144;  // 4 x 65536
    unsigned* mbits = (unsigned*)(wsb + ((size_t)37 << 20));            // 32 KB

    const size_t TOK = (size_t)BN * DMODEL;

    conv_all_kernel<<<9248, 256, 0, stream>>>(Wq, Wk, Wv, Wo, W1, W2, mask,
                                              wqT, wkT, wvT, wo_s, w1_s, w2_s, mbits);
    add_pos_kernel<<<(int)((TOK + 255) / 256), 256, 0, stream>>>(
        input, inputv, pos, x_f, x_b, xv_b, (int)TOK);

    for (int i = 0; i < NLAYER; i++) {
        const unsigned short* WqT_i = wqT + (size_t)i * 65536;
        const unsigned short* WkT_i = wkT + (size_t)i * 65536;
        const unsigned short* WvT_i = wvT + (size_t)i * 65536;
        const unsigned short* Wo_i  = wo_s + (size_t)i * 65536;
        const unsigned short* W1_i  = w1_s + (size_t)i * 262144;
        const unsigned short* W2_i  = w2_s + (size_t)i * 65536;

        qkv_mfma_kernel<<<dim3(6, 64), 256, 0, stream>>>(
            x_b, xv_b, WqT_i, WkT_i, WvT_i,
            bq + i * DMODEL, bk + i * DMODEL, bv + i * DMODEL,
            qb_b, kb_b, vb_b);

        attn_mfma_kernel<<<BDIM * NHEAD * 8, 256, 0, stream>>>(
            qb_b, kb_b, vb_b, ab_f, mbits, (i & 1));

        ffn_fused_kernel<<<BN / 16, 512, 0, stream>>>(
            ab_f, Wo_i, W1_i, W2_i,
            bo + i * DMODEL, g1 + i * DMODEL, be1 + i * DMODEL,
            b1 + i * DFF, b2 + i * (DMODEL / 2),
            g2 + i * DMODEL, be2 + i * DMODEL,
            gf, bff, x_f, x_b, out, (i == NLAYER - 1) ? 1 : 0);
    }
}

// Round 17
// 374.489 us; speedup vs baseline: 1.0302x; 1.0302x over previous
//
#include <hip/hip_runtime.h>
#include <hip/hip_bf16.h>
#include <math.h>

// Problem constants (LightGFormer): B=16, N=512, D=256, L=4, H=8, dk=32, Dff=1024
#define BDIM 16
#define NSEQ 512
#define DMODEL 256
#define NLAYER 4
#define NHEAD 8
#define DK 32
#define DFF 1024
#define BN (BDIM * NSEQ)          // 8192 tokens
#define ND (NSEQ * DMODEL)        // 131072

typedef __bf16 bf16x8 __attribute__((ext_vector_type(8)));
typedef float floatx4 __attribute__((ext_vector_type(4)));
typedef unsigned uint32x2 __attribute__((ext_vector_type(2)));

// RNE float->bf16 bits
static __device__ __forceinline__ unsigned short f2bf(float f) {
    unsigned u = __float_as_uint(f);
    unsigned r = (u + 0x7FFFu + ((u >> 16) & 1u)) >> 16;
    return (unsigned short)r;
}
static __device__ __forceinline__ float bf2f(unsigned short u) {
    return __uint_as_float(((unsigned)u) << 16);
}

// async 16-byte global->LDS copy (wave-uniform LDS base + lane*16 required)
static __device__ __forceinline__ void async_ld16(const unsigned short* g,
                                                  unsigned short* l) {
    __builtin_amdgcn_global_load_lds(
        (const __attribute__((address_space(1))) unsigned int*)g,
        (__attribute__((address_space(3))) unsigned int*)l, 16, 0, 0);
}

// sigmoid-form tanh-approx GELU, |err| < 1e-3 vs exact
static __device__ __forceinline__ float gelu_f(float c) {
    float u = 0.7978845608028654f * (c + 0.044715f * c * c * c);
    return c * (1.f / (1.f + __expf(-2.f * u)));
}

static __device__ __forceinline__ unsigned cvtpk(float lo, float hi) {
    unsigned r;
    asm("v_cvt_pk_bf16_f32 %0, %1, %2" : "=v"(r) : "v"(lo), "v"(hi));
    return r;
}

// ---------------------------------------------------------------------------
// Weight conversions + mask pack in ONE dispatch (R12-proven).
// blocks [0,3072)    : Wq/Wk/Wv [L,K,N]->[L,N,K] bf16 (qkv LDS kernel layout)
// blocks [3072,4096) : Wo  -> frag-direct wo_s
// blocks [4096,8192) : W1  -> frag-direct w1_s
// blocks [8192,9216) : W2  -> frag-direct w2_s
// blocks [9216,9248) : mask -> bitmask
// ---------------------------------------------------------------------------
__global__ void conv_all_kernel(const float* __restrict__ Wq, const float* __restrict__ Wk,
                                const float* __restrict__ Wv, const float* __restrict__ Wo,
                                const float* __restrict__ W1, const float* __restrict__ W2,
                                const int* __restrict__ mask,
                                unsigned short* __restrict__ wqT, unsigned short* __restrict__ wkT,
                                unsigned short* __restrict__ wvT,
                                unsigned short* __restrict__ wo_s,
                                unsigned short* __restrict__ w1_s, unsigned short* __restrict__ w2_s,
                                unsigned* __restrict__ bits) {
    int blk = blockIdx.x, tid = threadIdx.x;
    if (blk < 3072) {
        int i = blk * 256 + tid;
        int sel = i >> 18;
        int j = i & 262143;
        int l = j >> 16, rem = j & 65535, kk = rem >> 8, n = rem & 255;
        const float* src = sel == 0 ? Wq : sel == 1 ? Wk : Wv;
        unsigned short* dst = sel == 0 ? wqT : sel == 1 ? wkT : wvT;
        dst[(size_t)l * 65536 + n * 256 + kk] = f2bf(src[j]);
    } else if (blk < 4096) {
        int i = (blk - 3072) * 256 + tid;
        int l = i >> 16, o = i & 65535;
        int j = o & 7, quad = (o >> 3) & 3, l16 = (o >> 5) & 15;
        int kt = (o >> 9) & 7, cg = (o >> 12) & 15;
        int k = kt * 32 + (j >> 2) * 16 + quad * 4 + (j & 3);
        int dout = cg * 16 + l16;
        wo_s[(size_t)l * 65536 + o] = f2bf(Wo[(size_t)l * 65536 + k * 256 + dout]);
    } else if (blk < 8192) {
        int i = (blk - 4096) * 256 + tid;
        int l = i >> 18, o = i & 262143;
        int j = o & 7, quad = (o >> 3) & 3, l16 = (o >> 5) & 15;
        int kt = (o >> 9) & 7, cg = (o >> 12) & 63;
        int k = kt * 32 + (j >> 2) * 16 + quad * 4 + (j & 3);
        int dout = cg * 16 + l16;
        w1_s[(size_t)l * 262144 + o] = f2bf(W1[(size_t)l * 262144 + k * 1024 + dout]);
    } else if (blk < 9216) {
        int i = (blk - 8192) * 256 + tid;
        int l = i >> 16, o = i & 65535;
        int j = o & 7, quad = (o >> 3) & 3, l16 = (o >> 5) & 15;
        int kt = (o >> 9) & 15, cg = (o >> 13) & 7;
        int k = kt * 32 + (j >> 2) * 16 + quad * 4 + (j & 3);
        int dout = cg * 16 + l16;
        w2_s[(size_t)l * 65536 + o] = f2bf(W2[(size_t)l * 65536 + k * 128 + dout]);
    } else {
        int w = (blk - 9216) * 256 + tid;   // 0..8191
        int r = w >> 4, wi = w & 15;
        const int* src = mask + r * NSEQ + wi * 32;
        unsigned acc = 0;
#pragma unroll
        for (int j = 0; j < 32; j++) acc |= (src[j] != 0 ? 1u : 0u) << j;
        bits[w] = acc;
    }
}

// ---------------------------------------------------------------------------
// x = input + pos (fp32 + bf16 row-major) ; xv = input_v + pos (bf16 only)
// ---------------------------------------------------------------------------
__global__ void add_pos_kernel(const float* __restrict__ in,
                               const float* __restrict__ inv,
                               const float* __restrict__ pos,
                               float* __restrict__ x,
                               unsigned short* __restrict__ xb,
                               unsigned short* __restrict__ xvb,
                               int total) {
    int i = blockIdx.x * blockDim.x + threadIdx.x;
    if (i < total) {
        float pe = pos[i % ND];
        float a = in[i] + pe;
        float b = inv[i] + pe;
        x[i] = a;
        xb[i] = f2bf(a);
        xvb[i] = f2bf(b);
    }
}

// ---------------------------------------------------------------------------
// Fused QKV GEMM (proven R3/R4 structure). grid (6,64).
// ---------------------------------------------------------------------------
__global__ __launch_bounds__(256) void qkv_mfma_kernel(
        const unsigned short* __restrict__ xb,
        const unsigned short* __restrict__ xvb,
        const unsigned short* __restrict__ WqT, const unsigned short* __restrict__ WkT,
        const unsigned short* __restrict__ WvT,
        const float* __restrict__ bq, const float* __restrict__ bk,
        const float* __restrict__ bv,
        unsigned short* __restrict__ qo, unsigned short* __restrict__ ko,
        unsigned short* __restrict__ vo) {
    int proj = blockIdx.x >> 1;
    const unsigned short* A  = (proj == 2) ? xvb : xb;
    const unsigned short* Bt = (proj == 0) ? WqT : (proj == 1) ? WkT : WvT;
    const float* bias        = (proj == 0) ? bq  : (proj == 1) ? bk  : bv;
    unsigned short* Cb       = (proj == 0) ? qo  : (proj == 1) ? ko  : vo;
    float qscale = (proj == 0) ? 0.17677669529663687f : 1.f;

    __shared__ unsigned short As[128 * 32];
    __shared__ unsigned short Bs[128 * 32];
    int tid = threadIdx.x;
    int wave = tid >> 6, lane = tid & 63;
    int rowBase = blockIdx.y * 128, colBase = (blockIdx.x & 1) * 128;
    int m0w = (wave & 1) * 64, n0w = (wave >> 1) * 64;
    int lr = lane & 15, quad = lane >> 4;
    int qx = quad ^ (lr & 3);

    floatx4 acc[4][4];
#pragma unroll
    for (int mi = 0; mi < 4; mi++)
#pragma unroll
        for (int nj = 0; nj < 4; nj++) acc[mi][nj] = (floatx4)0.0f;

    for (int kt = 0; kt < DMODEL; kt += 32) {
#pragma unroll
        for (int t = 0; t < 2; t++) {
            int idx = t * 256 + tid;
            int row = idx >> 2, kv8 = ((idx ^ row) & 3) * 8;
            async_ld16(A + (size_t)(rowBase + row) * DMODEL + kt + kv8, &As[idx * 8]);
            async_ld16(Bt + (size_t)(colBase + row) * DMODEL + kt + kv8, &Bs[idx * 8]);
        }
        __syncthreads();
        bf16x8 af[4], bfr[4];
#pragma unroll
        for (int mi = 0; mi < 4; mi++)
            af[mi] = *(const bf16x8*)&As[(m0w + mi * 16 + lr) * 32 + qx * 8];
#pragma unroll
        for (int nj = 0; nj < 4; nj++)
            bfr[nj] = *(const bf16x8*)&Bs[(n0w + nj * 16 + lr) * 32 + qx * 8];
#pragma unroll
        for (int mi = 0; mi < 4; mi++)
#pragma unroll
            for (int nj = 0; nj < 4; nj++)
                acc[mi][nj] = __builtin_amdgcn_mfma_f32_16x16x32_bf16(
                    af[mi], bfr[nj], acc[mi][nj], 0, 0, 0);
        __syncthreads();
    }

#pragma unroll
    for (int mi = 0; mi < 4; mi++) {
#pragma unroll
        for (int r = 0; r < 4; r++) {
            int grow = rowBase + m0w + mi * 16 + quad * 4 + r;
#pragma unroll
            for (int nj = 0; nj < 4; nj++) {
                int gcol = colBase + n0w + nj * 16 + lr;
                float c = (acc[mi][nj][r] + bias[gcol]) * qscale;
                size_t off = ((size_t)((grow >> 9) * 8 + (gcol >> 5)) << 14)
                           + (size_t)(grow & 511) * 32 + (gcol & 31);
                Cb[off] = f2bf(c);
            }
        }
    }
}

// ---------------------------------------------------------------------------
// FUSED per-layer tail v5 (R12-proven): 512 threads / 8 waves per panel.
// ---------------------------------------------------------------------------
__global__ __launch_bounds__(512, 4) void ffn_fused_kernel(
        const unsigned short* __restrict__ ab_f,  // frag-direct attn out
        const unsigned short* __restrict__ wo_s,
        const unsigned short* __restrict__ w1_s,
        const unsigned short* __restrict__ w2_s,
        const float* __restrict__ bo,
        const float* __restrict__ g1, const float* __restrict__ be1,
        const float* __restrict__ b1,             // [1024]
        const float* __restrict__ b2,             // [128]
        const float* __restrict__ g2, const float* __restrict__ be2,
        const float* __restrict__ gf, const float* __restrict__ bf_,
        float* __restrict__ xf, unsigned short* __restrict__ xb,
        float* __restrict__ outF, int finalize) {
    __shared__ unsigned short X1s[8 * 512];    // 8KB  x1 tr-tiles [ct][colL*16+tok]
    __shared__ unsigned short Hs[16 * 512];    // 16KB h tr-tiles (per group)
    __shared__ float redA[16][8], redB[16][8];
    __shared__ float redC[16][8], redD[16][8];
    __shared__ float redE[16][8], redF[16][8];

    int tid = threadIdx.x;
    int w = tid >> 6, lane = tid & 63, l16 = lane & 15, quad = lane >> 4;
    int bid = blockIdx.x;                      // token panel (16 tokens)
    int rowBase = bid * 16;
    int fo = (l16 * 4 + quad) * 8;             // frag-direct lane offset (elems)

#define TR2(d0, d1, addr)                                                  \
    asm volatile("ds_read_b64_tr_b16 %0, %2\n\t"                           \
                 "ds_read_b64_tr_b16 %1, %2 offset:512"                    \
                 : "=&v"(d0), "=&v"(d1) : "v"(addr))

    // preload ALL scalar params + residual x0 now (latency hides under Phase A)
    float bo_r[2], g1_r[2], be1_r[2], g2_r[2], be2_r[2], gf_r[2], bfr_[2];
#pragma unroll
    for (int cg = 0; cg < 2; cg++) {
        int colA = w * 32 + cg * 16 + l16;
        bo_r[cg] = bo[colA]; g1_r[cg] = g1[colA]; be1_r[cg] = be1[colA];
        int colC = cg * 128 + w * 16 + l16;
        g2_r[cg] = g2[colC]; be2_r[cg] = be2[colC];
        gf_r[cg] = gf[colC]; bfr_[cg] = bf_[colC];
    }
    float b1_r[2][4];
#pragma unroll
    for (int g = 0; g < 2; g++)
#pragma unroll
        for (int c = 0; c < 4; c++)
            b1_r[g][c] = b1[g * 512 + w * 64 + c * 16 + l16];
    float b2_r = b2[w * 16 + l16];
    float x0r[4][2];
#pragma unroll
    for (int r = 0; r < 4; r++)
#pragma unroll
        for (int cg = 0; cg < 2; cg++)
            x0r[r][cg] = xf[(size_t)(rowBase + quad * 4 + r) * 256 + w * 32 + cg * 16 + l16];

    // ---- Phase A: x1 = LN1(x0 + ab@Wo + bo); wave owns 32 dout cols ----
    floatx4 accA[2];
    accA[0] = (floatx4)0.0f; accA[1] = (floatx4)0.0f;

    bf16x8 afQ[4], bwQ[4][2];
#pragma unroll
    for (int p = 0; p < 4; p++) {
        afQ[p] = *(const bf16x8*)(ab_f + ((size_t)bid * 8 + p) * 512 + fo);
#pragma unroll
        for (int cg = 0; cg < 2; cg++)
            bwQ[p][cg] = *(const bf16x8*)(wo_s + ((size_t)((w * 2 + cg) * 8 + p)) * 512 + fo);
    }

#pragma unroll
    for (int kt = 0; kt < 8; kt++) {
        int sl = kt & 3;
#pragma unroll
        for (int cg = 0; cg < 2; cg++)
            accA[cg] = __builtin_amdgcn_mfma_f32_16x16x32_bf16(afQ[sl], bwQ[sl][cg], accA[cg], 0, 0, 0);
        if (kt < 4) {
            afQ[sl] = *(const bf16x8*)(ab_f + ((size_t)bid * 8 + kt + 4) * 512 + fo);
#pragma unroll
            for (int cg = 0; cg < 2; cg++)
                bwQ[sl][cg] = *(const bf16x8*)(wo_s + ((size_t)((w * 2 + cg) * 8 + kt + 4)) * 512 + fo);
        }
    }

    // LN1 partials
#pragma unroll
    for (int r = 0; r < 4; r++) {
        int tok = quad * 4 + r;
        float s = 0.f, s2 = 0.f;
#pragma unroll
        for (int cg = 0; cg < 2; cg++) {
            float v = accA[cg][r] + bo_r[cg] + x0r[r][cg];
            accA[cg][r] = v; s += v; s2 += v * v;
        }
#pragma unroll
        for (int off = 1; off <= 8; off <<= 1) {
            s += __shfl_xor(s, off);
            s2 += __shfl_xor(s2, off);
        }
        if (l16 == 0) { redA[tok][w] = s; redB[tok][w] = s2; }
    }
    __syncthreads();
#pragma unroll
    for (int r = 0; r < 4; r++) {
        int tok = quad * 4 + r;
        float ts = 0.f, tq = 0.f;
#pragma unroll
        for (int ww = 0; ww < 8; ww++) { ts += redA[tok][ww]; tq += redB[tok][ww]; }
        float mean = ts * (1.f / 256.f);
        float var = tq * (1.f / 256.f) - mean * mean;
        float rstd = rsqrtf(var + 1e-5f);
#pragma unroll
        for (int cg = 0; cg < 2; cg++)
            accA[cg][r] = (accA[cg][r] - mean) * rstd * g1_r[cg] + be1_r[cg];
    }
    // write X1s tr-tile ct=w: value(tok,col) at [col>>5][(col&31)*16+tok]
#pragma unroll
    for (int cg = 0; cg < 2; cg++) {
        uint32x2 pk;
        pk[0] = cvtpk(accA[cg][0], accA[cg][1]);
        pk[1] = cvtpk(accA[cg][2], accA[cg][3]);
        *(uint32x2*)&X1s[w * 512 + (cg * 16 + l16) * 16 + quad * 4] = pk;
    }
    __syncthreads();

    unsigned x1addr = (unsigned)(size_t)&X1s[0] + (unsigned)(lane * 8);
    unsigned haddr  = (unsigned)(size_t)&Hs[0]  + (unsigned)(lane * 8);

    floatx4 y[2];
    y[0] = (floatx4)0.0f; y[1] = (floatx4)0.0f;

#pragma unroll
    for (int g = 0; g < 2; g++) {
        // ---- Phase B: h = gelu(x1 @ W1 + b1); wave owns 64 dff cols ----
        floatx4 accB[4];
#pragma unroll
        for (int c = 0; c < 4; c++) accB[c] = (floatx4)0.0f;

        uint32x2 tA0, tA1, tB0, tB1;
        TR2(tA0, tA1, x1addr);
        TR2(tB0, tB1, x1addr + 1024u);
        bf16x8 bwB[2][4];
#pragma unroll
        for (int p = 0; p < 2; p++)
#pragma unroll
            for (int c = 0; c < 4; c++)
                bwB[p][c] = *(const bf16x8*)(w1_s +
                    ((size_t)((g * 32 + w * 4 + c) * 8 + p)) * 512 + fo);

#pragma unroll
        for (int kt = 0; kt < 8; kt++) {
            if (kt < 7) asm volatile("s_waitcnt lgkmcnt(2)");
            else        asm volatile("s_waitcnt lgkmcnt(0)");
            __builtin_amdgcn_sched_barrier(0);
            union { bf16x8 v8; uint32x2 u[2]; } afu;
            if ((kt & 1) == 0) { afu.u[0] = tA0; afu.u[1] = tA1; }
            else               { afu.u[0] = tB0; afu.u[1] = tB1; }
            if (kt < 6) {
                if ((kt & 1) == 0) TR2(tA0, tA1, x1addr + (unsigned)((kt + 2) * 1024));
                else               TR2(tB0, tB1, x1addr + (unsigned)((kt + 2) * 1024));
            }
            int sl = kt & 1;
#pragma unroll
            for (int c = 0; c < 4; c++)
                accB[c] = __builtin_amdgcn_mfma_f32_16x16x32_bf16(afu.v8, bwB[sl][c], accB[c], 0, 0, 0);
            if (kt < 6) {
#pragma unroll
                for (int c = 0; c < 4; c++)
                    bwB[sl][c] = *(const bf16x8*)(w1_s +
                        ((size_t)((g * 32 + w * 4 + c) * 8 + kt + 2)) * 512 + fo);
            }
        }
        // epilogue B: bias+gelu, write Hs tr-tiles (wave-disjoint: ct = w*2+(c>>1))
#pragma unroll
        for (int c = 0; c < 4; c++) {
            float bb = b1_r[g][c];
            float o0 = gelu_f(accB[c][0] + bb);
            float o1 = gelu_f(accB[c][1] + bb);
            float o2 = gelu_f(accB[c][2] + bb);
            float o3 = gelu_f(accB[c][3] + bb);
            int ct = w * 2 + (c >> 1), colL = (c & 1) * 16 + l16;
            uint32x2 pk;
            pk[0] = cvtpk(o0, o1);
            pk[1] = cvtpk(o2, o3);
            *(uint32x2*)&Hs[ct * 512 + colL * 16 + quad * 4] = pk;
        }
        __syncthreads();

        // ---- Phase C: y[g] += h @ W2; wave owns 16 dout cols ----
        TR2(tA0, tA1, haddr);
        TR2(tB0, tB1, haddr + 1024u);
        bf16x8 bwC[4];
#pragma unroll
        for (int p = 0; p < 4; p++)
            bwC[p] = *(const bf16x8*)(w2_s + ((size_t)(w * 16 + p)) * 512 + fo);

#pragma unroll
        for (int kt = 0; kt < 16; kt++) {
            if (kt < 15) asm volatile("s_waitcnt lgkmcnt(2)");
            else         asm volatile("s_waitcnt lgkmcnt(0)");
            __builtin_amdgcn_sched_barrier(0);
            union { bf16x8 v8; uint32x2 u[2]; } afu;
            if ((kt & 1) == 0) { afu.u[0] = tA0; afu.u[1] = tA1; }
            else               { afu.u[0] = tB0; afu.u[1] = tB1; }
            if (kt < 14) {
                if ((kt & 1) == 0) TR2(tA0, tA1, haddr + (unsigned)((kt + 2) * 1024));
                else               TR2(tB0, tB1, haddr + (unsigned)((kt + 2) * 1024));
            }
            y[g] = __builtin_amdgcn_mfma_f32_16x16x32_bf16(afu.v8, bwC[kt & 3], y[g], 0, 0, 0);
            if (kt < 12)
                bwC[kt & 3] = *(const bf16x8*)(w2_s + ((size_t)(w * 16 + kt + 4)) * 512 + fo);
        }
        if (g == 0) __syncthreads();   // protect Hs before group 1 rewrites
    }
#undef TR2

    // ---- LN2 (+ optional final LN); lane holds cols g*128 + w*16 + l16 ----
#pragma unroll
    for (int r = 0; r < 4; r++) {
        int tok = quad * 4 + r;
        float s = 0.f, s2 = 0.f;
#pragma unroll
        for (int g = 0; g < 2; g++) {
            int col = g * 128 + w * 16 + l16;
            float x1v = bf2f(X1s[(col >> 5) * 512 + (col & 31) * 16 + tok]);
            float v = y[g][r] + b2_r + x1v;
            y[g][r] = v; s += v; s2 += v * v;
        }
#pragma unroll
        for (int off = 1; off <= 8; off <<= 1) {
            s += __shfl_xor(s, off);
            s2 += __shfl_xor(s2, off);
        }
        if (l16 == 0) { redC[tok][w] = s; redD[tok][w] = s2; }
    }
    __syncthreads();

    if (!finalize) {
#pragma unroll
        for (int r = 0; r < 4; r++) {
            int tok = quad * 4 + r;
            float ts = 0.f, tq = 0.f;
#pragma unroll
            for (int ww = 0; ww < 8; ww++) { ts += redC[tok][ww]; tq += redD[tok][ww]; }
            float mean = ts * (1.f / 256.f);
            float var = tq * (1.f / 256.f) - mean * mean;
            float rstd = rsqrtf(var + 1e-5f);
#pragma unroll
            for (int g = 0; g < 2; g++) {
                int col = g * 128 + w * 16 + l16;
                float o = (y[g][r] - mean) * rstd * g2_r[g] + be2_r[g];
                xf[(size_t)(rowBase + tok) * 256 + col] = o;
                xb[(size_t)(rowBase + tok) * 256 + col] = f2bf(o);
            }
        }
    } else {
#pragma unroll
        for (int r = 0; r < 4; r++) {
            int tok = quad * 4 + r;
            float ts = 0.f, tq = 0.f;
#pragma unroll
            for (int ww = 0; ww < 8; ww++) { ts += redC[tok][ww]; tq += redD[tok][ww]; }
            float mean = ts * (1.f / 256.f);
            float var = tq * (1.f / 256.f) - mean * mean;
            float rstd = rsqrtf(var + 1e-5f);
            float s3 = 0.f, q3 = 0.f;
#pragma unroll
            for (int g = 0; g < 2; g++) {
                float o = (y[g][r] - mean) * rstd * g2_r[g] + be2_r[g];
                y[g][r] = o; s3 += o; q3 += o * o;
            }
#pragma unroll
            for (int off = 1; off <= 8; off <<= 1) {
                s3 += __shfl_xor(s3, off);
                q3 += __shfl_xor(q3, off);
            }
            if (l16 == 0) { redE[tok][w] = s3; redF[tok][w] = q3; }
        }
        __syncthreads();
#pragma unroll
        for (int r = 0; r < 4; r++) {
            int tok = quad * 4 + r;
            float ts = 0.f, tq = 0.f;
#pragma unroll
            for (int ww = 0; ww < 8; ww++) { ts += redE[tok][ww]; tq += redF[tok][ww]; }
            float mean = ts * (1.f / 256.f);
            float var = tq * (1.f / 256.f) - mean * mean;
            float rstd = rsqrtf(var + 1e-5f);
#pragma unroll
            for (int g = 0; g < 2; g++) {
                int col = g * 128 + w * 16 + l16;
                outF[(size_t)(rowBase + tok) * 256 + col]
                    = (y[g][r] - mean) * rstd * gf_r[g] + bfr_[g];
            }
        }
    }
}

// ---------------------------------------------------------------------------
// MFMA attention v2 (pair-batched, R12-proven). __launch_bounds__(256, 4)
// RESTORED: the R16 experiment showed dropping the min-waves clause costs
// ~8 us (occupancy drops below 4 blocks/CU; occupancy > regalloc freedom
// in this latency-bound kernel).
// ---------------------------------------------------------------------------
__global__ __launch_bounds__(256, 4) void attn_mfma_kernel(
        const unsigned short* __restrict__ q, const unsigned short* __restrict__ k,
        const unsigned short* __restrict__ v, unsigned short* __restrict__ ab_f,
        const unsigned* __restrict__ mbits_g, int use_mask) {
    int bid = blockIdx.x;
    int qg = bid >> 7;          // 0..7
    int bh = bid & 127;         // XCD = bh & 7 = h
    int h = bh & 7, b = bh >> 3;
    int tid = threadIdx.x;

    __shared__ unsigned short Vs[2][NSEQ * 16];     // 32KB  [db][k*16+d]

    const unsigned short* kbase = k + (size_t)(b * 8 + h) * (NSEQ * DK);
    const unsigned short* vbase = v + (size_t)(b * 8 + h) * (NSEQ * DK);

#pragma unroll
    for (int db = 0; db < 2; db++) {
#pragma unroll
        for (int t = 0; t < 4; t++) {
            int c = t * 256 + tid;                  // 0..1023
            int kk = c >> 1, half = c & 1;
            async_ld16(vbase + (size_t)kk * 32 + db * 16 + half * 8,
                       &Vs[db][c * 8]);
        }
    }

    int wave = tid >> 6, lane = tid & 63, l16 = lane & 15, quad = lane >> 4;
    int qbase = qg * 64 + wave * 16;

    bf16x8 qf = *(const bf16x8*)(q + ((size_t)(b * 8 + h) * NSEQ + qbase + l16) * 32 + quad * 8);

    unsigned mw[16];
    if (use_mask) {
        const uint4* mr = (const uint4*)(mbits_g + (size_t)(qbase + l16) * 16);
#pragma unroll
        for (int w = 0; w < 4; w++) *(uint4*)&mw[w * 4] = mr[w];
    } else {
#pragma unroll
        for (int w = 0; w < 16; w++) mw[w] = 0;
    }
    __syncthreads();

    unsigned va0 = (unsigned)(size_t)&Vs[0][0] + (unsigned)(lane * 8);
    unsigned va1 = (unsigned)(size_t)&Vs[1][0] + (unsigned)(lane * 8);

    const unsigned short* kfrag = kbase + (size_t)l16 * DK + quad * 8;

    floatx4 oT0 = (floatx4)0.f, oT1 = (floatx4)0.f;
    float m_run = -INFINITY, l_part = 0.f;

    uint32x2 t00, t01, t02, t03, t10, t11, t12, t13;
    // 8 tr-reads for pair cp: tiles 2cp (offsets 0,512) and 2cp+1 (1024,1536)
#define TR_ISSUE8(cp)                                                      \
    asm volatile("ds_read_b64_tr_b16 %0, %8\n\t"                           \
                 "ds_read_b64_tr_b16 %1, %8 offset:512\n\t"                \
                 "ds_read_b64_tr_b16 %2, %8 offset:1024\n\t"               \
                 "ds_read_b64_tr_b16 %3, %8 offset:1536\n\t"               \
                 "ds_read_b64_tr_b16 %4, %9\n\t"                           \
                 "ds_read_b64_tr_b16 %5, %9 offset:512\n\t"                \
                 "ds_read_b64_tr_b16 %6, %9 offset:1024\n\t"               \
                 "ds_read_b64_tr_b16 %7, %9 offset:1536"                   \
                 : "=&v"(t00), "=&v"(t01), "=&v"(t02), "=&v"(t03),         \
                   "=&v"(t10), "=&v"(t11), "=&v"(t12), "=&v"(t13)          \
                 : "v"(va0 + (unsigned)((cp) * 2048)),                     \
                   "v"(va1 + (unsigned)((cp) * 2048)))
    TR_ISSUE8(0);

    bf16x8 k0 = *(const bf16x8*)(kfrag);
    bf16x8 k1 = *(const bf16x8*)(kfrag + 16 * DK);
    bf16x8 k2 = *(const bf16x8*)(kfrag + 32 * DK);
    bf16x8 k3 = *(const bf16x8*)(kfrag + 48 * DK);

#pragma unroll
    for (int cp = 0; cp < 8; cp++) {
        floatx4 s0 = __builtin_amdgcn_mfma_f32_16x16x32_bf16(k0, qf, (floatx4)0.f, 0, 0, 0);
        floatx4 s1 = __builtin_amdgcn_mfma_f32_16x16x32_bf16(k1, qf, (floatx4)0.f, 0, 0, 0);
        floatx4 s2 = __builtin_amdgcn_mfma_f32_16x16x32_bf16(k2, qf, (floatx4)0.f, 0, 0, 0);
        floatx4 s3 = __builtin_amdgcn_mfma_f32_16x16x32_bf16(k3, qf, (floatx4)0.f, 0, 0, 0);

        bf16x8 k0n, k1n, k2n, k3n;
        if (cp < 7) {
            const unsigned short* kn = kfrag + (size_t)((cp + 1) * 64) * DK;
            k0n = *(const bf16x8*)(kn);
            k1n = *(const bf16x8*)(kn + 16 * DK);
            k2n = *(const bf16x8*)(kn + 32 * DK);
            k3n = *(const bf16x8*)(kn + 48 * DK);
        }

        float sv[16];
#pragma unroll
        for (int r = 0; r < 4; r++) {
            sv[r] = s0[r]; sv[4 + r] = s1[r];
            sv[8 + r] = s2[r]; sv[12 + r] = s3[r];
        }
        if (use_mask) {
            unsigned wb0 = mw[2 * cp], wb1 = mw[2 * cp + 1];
#pragma unroll
            for (int r = 0; r < 4; r++) {
                if ((wb0 >> (quad * 4 + r)) & 1)        sv[r]      = -INFINITY;
                if ((wb0 >> (16 + quad * 4 + r)) & 1)   sv[4 + r]  = -INFINITY;
                if ((wb1 >> (quad * 4 + r)) & 1)        sv[8 + r]  = -INFINITY;
                if ((wb1 >> (16 + quad * 4 + r)) & 1)   sv[12 + r] = -INFINITY;
            }
        }
        float mx = sv[0];
#pragma unroll
        for (int j = 1; j < 16; j++) mx = fmaxf(mx, sv[j]);
        mx = fmaxf(mx, __shfl_xor(mx, 16));
        mx = fmaxf(mx, __shfl_xor(mx, 32));
        if (!__all(mx <= m_run)) {
            float mnew = fmaxf(m_run, mx);
            float corr = (m_run == mnew) ? 1.f : __expf(m_run - mnew);
            l_part *= corr;
            oT0 *= corr; oT1 *= corr;
            m_run = mnew;
        }
        float p[16];
#pragma unroll
        for (int j = 0; j < 16; j++) {
            float e = __expf(sv[j] - m_run);
            p[j] = (sv[j] > -INFINITY) ? e : 0.f;
            l_part += p[j];
        }
        union { bf16x8 v8; unsigned u[4]; } pf0, pf1;
#pragma unroll
        for (int j = 0; j < 4; j++) {
            pf0.u[j] = cvtpk(p[2 * j], p[2 * j + 1]);
            pf1.u[j] = cvtpk(p[8 + 2 * j], p[8 + 2 * j + 1]);
        }

        asm volatile("s_waitcnt lgkmcnt(0)");
        __builtin_amdgcn_sched_barrier(0);
        union { bf16x8 v8; uint32x2 u[2]; } av0, av1, av2, av3;
        av0.u[0] = t00; av0.u[1] = t01;   // tile 2cp,   d block 0
        av2.u[0] = t02; av2.u[1] = t03;   // tile 2cp+1, d block 0
        av1.u[0] = t10; av1.u[1] = t11;   // tile 2cp,   d block 1
        av3.u[0] = t12; av3.u[1] = t13;   // tile 2cp+1, d block 1

        oT0 = __builtin_amdgcn_mfma_f32_16x16x32_bf16(av0.v8, pf0.v8, oT0, 0, 0, 0);
        oT1 = __builtin_amdgcn_mfma_f32_16x16x32_bf16(av1.v8, pf0.v8, oT1, 0, 0, 0);
        oT0 = __builtin_amdgcn_mfma_f32_16x16x32_bf16(av2.v8, pf1.v8, oT0, 0, 0, 0);
        oT1 = __builtin_amdgcn_mfma_f32_16x16x32_bf16(av3.v8, pf1.v8, oT1, 0, 0, 0);
        if (cp < 7) TR_ISSUE8(cp + 1);
        k0 = k0n; k1 = k1n; k2 = k2n; k3 = k3n;
    }
#undef TR_ISSUE8

    float l = l_part;
    l += __shfl_xor(l, 16);
    l += __shfl_xor(l, 32);
    float invl = (l > 0.f) ? 1.f / l : 0.f;

    // frag-direct store: panel = global_token>>4, tile kt = h
    uint4 val;
    val.x = cvtpk(oT0[0] * invl, oT0[1] * invl);
    val.y = cvtpk(oT0[2] * invl, oT0[3] * invl);
    val.z = cvtpk(oT1[0] * invl, oT1[1] * invl);
    val.w = cvtpk(oT1[2] * invl, oT1[3] * invl);
    size_t panel = (size_t)b * 32 + qg * 4 + wave;
    *(uint4*)(ab_f + (panel * 8 + h) * 512 + (l16 * 4 + quad) * 8) = val;
}

// ---------------------------------------------------------------------------
extern "C" void kernel_launch(void* const* d_in, const int* in_sizes, int n_in,
                              void* d_out, int out_size, void* d_ws, size_t ws_size,
                              hipStream_t stream) {
    const float* input  = (const float*)d_in[0];
    const float* inputv = (const float*)d_in[1];
    const float* pos    = (const float*)d_in[2];
    const float* Wq = (const float*)d_in[3];
    const float* bq = (const float*)d_in[4];
    const float* Wk = (const float*)d_in[5];
    const float* bk = (const float*)d_in[6];
    const float* Wv = (const float*)d_in[7];
    const float* bv = (const float*)d_in[8];
    const float* Wo = (const float*)d_in[9];
    const float* bo = (const float*)d_in[10];
    const float* W1 = (const float*)d_in[11];
    const float* b1 = (const float*)d_in[12];
    const float* W2 = (const float*)d_in[13];
    const float* b2 = (const float*)d_in[14];
    const float* g1 = (const float*)d_in[15];
    const float* be1 = (const float*)d_in[16];
    const float* g2 = (const float*)d_in[17];
    const float* be2 = (const float*)d_in[18];
    const float* gf = (const float*)d_in[19];
    const float* bff = (const float*)d_in[20];
    const int* mask = (const int*)d_in[21];

    float* out = (float*)d_out;

    // Workspace layout (bytes), ~37 MB
    char* wsb = (char*)d_ws;
    float* x_f  = (float*)(wsb + ((size_t)0 << 20));                    // 8 MB
    unsigned short* x_b  = (unsigned short*)(wsb + ((size_t)8 << 20));  // 4 MB
    unsigned short* xv_b = (unsigned short*)(wsb + ((size_t)12 << 20)); // 4 MB
    unsigned short* qb_b = (unsigned short*)(wsb + ((size_t)16 << 20)); // 4 MB
    unsigned short* kb_b = (unsigned short*)(wsb + ((size_t)20 << 20)); // 4 MB
    unsigned short* vb_b = (unsigned short*)(wsb + ((size_t)24 << 20)); // 4 MB
    unsigned short* ab_f = (unsigned short*)(wsb + ((size_t)28 << 20)); // 4 MB
    unsigned short* wqT = (unsigned short*)(wsb + ((size_t)32 << 20));
    unsigned short* wkT = wqT + (size_t)4 * 65536;
    unsigned short* wvT = wkT + (size_t)4 * 65536;
    unsigned short* wo_s = wvT + (size_t)4 * 65536;
    unsigned short* w1_s = wo_s + (size_t)4 * 65536;   // 4 x 262144
    unsigned short* w2_s = w1_s + (size_t)4 * 262144;  // 4 x 65536
    unsigned* mbits = (unsigned*)(wsb + ((size_t)37 << 20));            // 32 KB

    const size_t TOK = (size_t)BN * DMODEL;

    conv_all_kernel<<<9248, 256, 0, stream>>>(Wq, Wk, Wv, Wo, W1, W2, mask,
                                              wqT, wkT, wvT, wo_s, w1_s, w2_s, mbits);
    add_pos_kernel<<<(int)((TOK + 255) / 256), 256, 0, stream>>>(
        input, inputv, pos, x_f, x_b, xv_b, (int)TOK);

    for (int i = 0; i < NLAYER; i++) {
        const unsigned short* WqT_i = wqT + (size_t)i * 65536;
        const unsigned short* WkT_i = wkT + (size_t)i * 65536;
        const unsigned short* WvT_i = wvT + (size_t)i * 65536;
        const unsigned short* Wo_i  = wo_s + (size_t)i * 65536;
        const unsigned short* W1_i  = w1_s + (size_t)i * 262144;
        const unsigned short* W2_i  = w2_s + (size_t)i * 65536;

        qkv_mfma_kernel<<<dim3(6, 64), 256, 0, stream>>>(
            x_b, xv_b, WqT_i, WkT_i, WvT_i,
            bq + i * DMODEL, bk + i * DMODEL, bv + i * DMODEL,
            qb_b, kb_b, vb_b);

        attn_mfma_kernel<<<BDIM * NHEAD * 8, 256, 0, stream>>>(
            qb_b, kb_b, vb_b, ab_f, mbits, (i & 1));

        ffn_fused_kernel<<<BN / 16, 512, 0, stream>>>(
            ab_f, Wo_i, W1_i, W2_i,
            bo + i * DMODEL, g1 + i * DMODEL, be1 + i * DMODEL,
            b1 + i * DFF, b2 + i * (DMODEL / 2),
            g2 + i * DMODEL, be2 + i * DMODEL,
            gf, bff, x_f, x_b, out, (i == NLAYER - 1) ? 1 : 0);
    }
}